// Round 21
// baseline (902.756 us; speedup 1.0000x reference)
//
#include <hip/hip_runtime.h>

#define N_NODES 100000
#define N_EDGES 200000
#define N_GRAPHS 4000
#define F_IN 44
#define HDIM 256
#define EDIM 512
#define NLAYERS 4

typedef float floatx4 __attribute__((ext_vector_type(4)));
typedef short bhalf8 __attribute__((ext_vector_type(8)));

__device__ __forceinline__ unsigned short f2bf(float f) {
    unsigned int u = __float_as_uint(f);
    u += 0x7FFFu + ((u >> 16) & 1u);          // RNE
    return (unsigned short)(u >> 16);
}
__device__ __forceinline__ float bf2f(unsigned short s) {
    return __uint_as_float(((unsigned int)s) << 16);
}

// async global->LDS, 16B/lane. ldst wave-uniform base; gsrc per-lane.
__device__ __forceinline__ void gload16(const void* gsrc, void* ldst) {
    __builtin_amdgcn_global_load_lds(
        (const __attribute__((address_space(1))) void*)gsrc,
        (__attribute__((address_space(3))) void*)ldst, 16, 0, 0);
}

// ---------------- zero fill ----------------
__global__ void zero_kernel(float* __restrict__ p, size_t n4) {
    size_t i = (size_t)blockIdx.x * blockDim.x + threadIdx.x;
    const size_t stride = (size_t)gridDim.x * blockDim.x;
    const float4 z = make_float4(0.f, 0.f, 0.f, 0.f);
    for (; i < n4; i += stride) ((float4*)p)[i] = z;
}

// ------- xprep: x fp32 [N][44] -> xb bf16 [N][64] zero-padded (coalesced 8B writes) -------
__global__ void xprep_kernel(const float* __restrict__ x, unsigned short* __restrict__ xb) {
    int idx = blockIdx.x * 256 + threadIdx.x;
    const int total = N_NODES * 16;               // 16 x ushort4 slots per node
    const int stride = gridDim.x * 256;
    for (; idx < total; idx += stride) {
        const int n = idx >> 4, k4 = idx & 15;
        ushort4 v = make_ushort4(0, 0, 0, 0);
        if (k4 < F_IN / 4) {                      // 11 valid float4 slots
            const float4 xv = *(const float4*)(x + (size_t)n * F_IN + k4 * 4);
            v.x = f2bf(xv.x); v.y = f2bf(xv.y); v.z = f2bf(xv.z); v.w = f2bf(xv.w);
        }
        *(ushort4*)(xb + (size_t)n * 64 + k4 * 4) = v;
    }
}

// ---------------- CSR build ----------------
__global__ void hist_kernel(const int* __restrict__ dst, int* __restrict__ deg) {
    const int e = blockIdx.x * 256 + threadIdx.x;
    if (e < N_EDGES) atomicAdd(&deg[dst[e]], 1);
}

__global__ void scan1_kernel(const int* __restrict__ deg, int* __restrict__ row_ptr,
                             int* __restrict__ blk) {
    __shared__ int s[256];
    const int i = blockIdx.x * 256 + threadIdx.x;
    s[threadIdx.x] = (i < N_NODES) ? deg[i] : 0;
    __syncthreads();
    for (int off = 1; off < 256; off <<= 1) {
        int t = (threadIdx.x >= off) ? s[threadIdx.x - off] : 0;
        __syncthreads();
        s[threadIdx.x] += t;
        __syncthreads();
    }
    if (i < N_NODES) row_ptr[i + 1] = s[threadIdx.x];
    if (threadIdx.x == 255) blk[blockIdx.x] = s[255];
}

__global__ void scan2_kernel(int* __restrict__ blk, int nb) {
    if (threadIdx.x == 0 && blockIdx.x == 0) {
        int run = 0;
        for (int b = 0; b < nb; ++b) { const int t = blk[b]; blk[b] = run; run += t; }
    }
}

__global__ void scan3_kernel(int* __restrict__ row_ptr, const int* __restrict__ blk) {
    const int i = blockIdx.x * 256 + threadIdx.x;
    if (i < N_NODES) row_ptr[i + 1] += blk[i >> 8];
    if (i == 0) row_ptr[0] = 0;
}

__global__ void cursor_kernel(const int* __restrict__ row_ptr, int* __restrict__ cursor) {
    const int i = blockIdx.x * 256 + threadIdx.x;
    if (i < N_NODES) cursor[i] = row_ptr[i];
}

__global__ void fill_kernel(const int* __restrict__ src, const int* __restrict__ dst,
                            int* __restrict__ cursor, int* __restrict__ eids) {
    const int e = blockIdx.x * 256 + threadIdx.x;
    if (e < N_EDGES) {
        const int pos = atomicAdd(&cursor[dst[e]], 1);
        eids[pos] = src[e];
    }
}

// ------- segment sort: deterministic eids order (replay-stable fp32 sums) -------
__global__ void sort_kernel(const int* __restrict__ row_ptr, int* __restrict__ eids) {
    const int n = blockIdx.x * 256 + threadIdx.x;
    if (n < N_NODES) {
        const int s = row_ptr[n], e = row_ptr[n + 1];
        for (int i = s + 1; i < e; ++i) {
            const int v = eids[i];
            int j = i - 1;
            while (j >= s && eids[j] > v) { eids[j + 1] = eids[j]; --j; }
            eids[j + 1] = v;
        }
    }
}

// ------- gather: z = h + sum_neigh h (bf16 h, fp32 acc); write bf16 [n][HDIM] -------
__global__ void gather_kernel(const unsigned short* __restrict__ h,
                              const int* __restrict__ row_ptr,
                              const int* __restrict__ eids, unsigned short* __restrict__ z) {
    const int tid = threadIdx.x;
    const int n = blockIdx.x * 4 + (tid >> 6);
    const int t = tid & 63;
    const ushort4* h4 = (const ushort4*)h;          // 4 bf16 per lane (8B)
    ushort4 hv = h4[(size_t)n * 64 + t];
    float4 acc = make_float4(bf2f(hv.x), bf2f(hv.y), bf2f(hv.z), bf2f(hv.w));
    const int s = row_ptr[n], e = row_ptr[n + 1];
    for (int i = s; i < e; ++i) {
        const ushort4 v = h4[(size_t)eids[i] * 64 + t];
        acc.x += bf2f(v.x); acc.y += bf2f(v.y);
        acc.z += bf2f(v.z); acc.w += bf2f(v.w);
    }
    ushort4 pk;
    pk.x = f2bf(acc.x); pk.y = f2bf(acc.y);
    pk.z = f2bf(acc.z); pk.w = f2bf(acc.w);
    ((ushort4*)(z + (size_t)n * HDIM))[t] = pk;
}

// ------- fused weight prep: all weights -> transposed [N][K] bf16, one dispatch -------
__global__ void wprep_all(const float* __restrict__ W1, const float* __restrict__ W2,
                          const float* __restrict__ Wf1, const float* __restrict__ Wf2,
                          const float* __restrict__ Wa,
                          unsigned short* __restrict__ t1, unsigned short* __restrict__ t2,
                          unsigned short* __restrict__ tf1, unsigned short* __restrict__ tf2,
                          unsigned short* __restrict__ tat) {
    const int WSZ = HDIM * 2 * HDIM;                 // 131072
    const int T0 = 8 * WSZ;                          // W1+W2
    const int T1 = T0 + HDIM * HDIM;                 // +Wf1
    const int T2 = T1 + HDIM * EDIM;                 // +Wf2
    const int T3 = T2 + 64 * HDIM;                   // +W_atom (padded K=64)
    const int stride = gridDim.x * 256;
    for (int idx = blockIdx.x * 256 + threadIdx.x; idx < T3; idx += stride) {
        if (idx < 4 * WSZ) {                         // W1: K=256, N=512 -> t1 [512][256]
            const int l = idx >> 17, e = idx & (WSZ - 1);
            const int k = e >> 9, n = e & 511;
            t1[(size_t)l * WSZ + n * HDIM + k] = f2bf(W1[idx]);
        } else if (idx < T0) {                       // W2: K=512, N=256 -> t2 [256][512]
            const int r = idx - 4 * WSZ;
            const int l = r >> 17, e = r & (WSZ - 1);
            const int k = e >> 8, n = e & 255;
            t2[(size_t)l * WSZ + n * EDIM + k] = f2bf(W2[r]);
        } else if (idx < T1) {                       // Wf1 -> tf1 [256][256]
            const int e = idx - T0;
            const int k = e >> 8, n = e & 255;
            tf1[n * HDIM + k] = f2bf(Wf1[e]);
        } else if (idx < T2) {                       // Wf2: K=256, N=512 -> tf2 [512][256]
            const int e = idx - T1;
            const int k = e >> 9, n = e & 511;
            tf2[n * HDIM + k] = f2bf(Wf2[e]);
        } else {                                     // W_atom: [44][256] -> tat [256][64] pad0
            const int e = idx - T2;                  // e over 64*256, k-major per n
            const int n = e >> 6, k = e & 63;
            tat[n * 64 + k] = (k < F_IN) ? f2bf(Wa[k * HDIM + n]) : (unsigned short)0;
        }
    }
}

// ======== PERSISTENT MULTI-TILE MFMA GEMM: C = act(A @ B + bias) ========
// A [M][KK] bf16 row-major, BT [N][KK] bf16, where KK = NT*64 is now DERIVED from
// the NT template parameter inside the kernel (r20 ABORT/garbage root cause: the
// redundant runtime KK argument disagreed with NT at one call site -> strided A
// reads into unrelated workspace. Invariant now unviolable by construction).
// Each block owns a CONTIGUOUS range of col-fastest 128x128 tiles and runs ONE
// continuous counted-vmcnt(8) pipeline across all of them (r18 lesson: short-K
// blocks were ~50% prologue/epilogue). The next tile's first stage is in flight
// DURING the current tile's epilogue. Epilogue (OUT=2) reuses the just-consumed
// ping buffer as scratch in two 64-row halves; explicit lgkmcnt(0) (DS-only —
// the vmcnt prefetch stays in flight) before each raw barrier (r19 lesson).
// Per-tile K-order identical to r17 -> bit-identical results.
// OUT: 0 = fp32 (direct store), 2 = bf16+relu via LDS-staged coalesced writes.
template <int OUT, int NT>
__global__ __launch_bounds__(256)
void gemm_mt(const unsigned short* __restrict__ A, const unsigned short* __restrict__ BT,
             const float* __restrict__ bias, float* __restrict__ C,
             unsigned short* __restrict__ Z, int M, int N, int tpb) {
    constexpr int KK = NT * 64;                      // single source of truth
    __shared__ __align__(16) unsigned short lds[32768];   // 2 x (A 8192us | B 8192us)

    const int ncol = N >> 7;
    const int nrow = (M + 127) >> 7;
    const int ntile = nrow * ncol;
    const int G = gridDim.x;
    int b = blockIdx.x;
    {   // bijective XCD remap (m204)
        const int q = G >> 3, r = G & 7;
        const int xx = b & 7, o = b >> 3;
        b = (xx < r ? xx * (q + 1) : r * (q + 1) + (xx - r) * q) + o;
    }
    const int tile0 = b * tpb;
    if (tile0 >= ntile) return;
    const int tend = (tile0 + tpb < ntile) ? tile0 + tpb : ntile;
    const int S = (tend - tile0) * NT;               // flat pipeline steps

    const int tid = threadIdx.x;
    const int lane = tid & 63;
    const int w = tid >> 6;
    const int wr = w >> 1, wc = w & 1;
    const int lr = lane & 15;
    const int l4 = lane >> 4;
    const int rgrp = l4 * 4;
    const int srow = tid >> 3;                              // 0..31
    const int sgran = ((tid & 7) ^ (srow & 7)) << 3;        // pre-swizzled src granule

    // stage flat step s into ping buffer (s&1)
    auto stage = [&](int s) {
        const int tau = tile0 + s / NT;
        const int t = s % NT;                               // NT constexpr -> shifts
        const int r0 = (tau / ncol) << 7;
        const int c0 = (tau % ncol) << 7;
        const int k0 = t << 6;
        unsigned short* la = &lds[(s & 1) * 16384];
        unsigned short* lb = la + 8192;
#pragma unroll
        for (int pass = 0; pass < 4; ++pass) {
            const int r = (pass << 5) + srow;               // 0..127
            int ar = r0 + r; if (ar >= M) ar = M - 1;       // clamp (uniform vmcnt)
            gload16(A + (size_t)ar * KK + k0 + sgran, &la[(pass << 11) + (w << 9)]);
            gload16(BT + (size_t)(c0 + r) * KK + k0 + sgran, &lb[(pass << 11) + (w << 9)]);
        }
    };

    floatx4 acc[4][4];
#pragma unroll
    for (int m = 0; m < 4; ++m)
#pragma unroll
        for (int n = 0; n < 4; ++n) acc[m][n] = (floatx4){0.f, 0.f, 0.f, 0.f};

    stage(0);
    if (S > 1) stage(1);
    for (int s = 0; s < S; ++s) {
        const int tau = tile0 + s / NT;
        const int t = s % NT;
        const int row0 = (tau / ncol) << 7;
        const int col0 = (tau % ncol) << 7;

        if (s + 1 < S) {
            asm volatile("s_waitcnt vmcnt(8)" ::: "memory");   // step s landed; s+1 flying
        } else {
            asm volatile("s_waitcnt vmcnt(0)" ::: "memory");
        }
        __builtin_amdgcn_s_barrier();

        const unsigned short* la = &lds[(s & 1) * 16384];
        const unsigned short* lb = la + 8192;
#pragma unroll
        for (int ss = 0; ss < 2; ++ss) {
            const int pg = (((ss << 2) + l4) ^ (lr & 7)) << 3;
            bhalf8 fa[4], fb[4];
#pragma unroll
            for (int m = 0; m < 4; ++m)
                fa[m] = *(const bhalf8*)&la[((wr << 6) + (m << 4) + lr) * 64 + pg];
#pragma unroll
            for (int n = 0; n < 4; ++n)
                fb[n] = *(const bhalf8*)&lb[((wc << 6) + (n << 4) + lr) * 64 + pg];
#pragma unroll
            for (int m = 0; m < 4; ++m)
#pragma unroll
                for (int n = 0; n < 4; ++n)
                    acc[m][n] = __builtin_amdgcn_mfma_f32_16x16x32_bf16(fa[m], fb[n], acc[m][n], 0, 0, 0);
        }

        asm volatile("s_waitcnt lgkmcnt(0)" ::: "memory");  // frag ds_reads done
        __builtin_amdgcn_s_barrier();    // all waves done reading buffer (s&1)

        if (t == NT - 1) {
            // ---- tile epilogue; scratch = just-consumed buffer (s&1); next tile's
            // first stage (s+1) is in flight into the OTHER buffer ----
            unsigned short* scratch = &lds[(s & 1) * 16384];
            if (OUT == 2) {
#pragma unroll
                for (int half = 0; half < 2; ++half) {      // [64][136] us fits 16K us
                    if (wr == half) {
#pragma unroll
                        for (int n = 0; n < 4; ++n) {
                            const int colt = (wc << 6) + (n << 4) + lr;
                            const float bv = bias[col0 + colt];
#pragma unroll
                            for (int m = 0; m < 4; ++m) {
#pragma unroll
                                for (int j = 0; j < 4; ++j)
                                    scratch[((m << 4) + rgrp + j) * 136 + colt] =
                                        f2bf(fmaxf(acc[m][n][j] + bv, 0.f));
                            }
                        }
                    }
                    asm volatile("s_waitcnt lgkmcnt(0)" ::: "memory");  // writes landed
                    __builtin_amdgcn_s_barrier();
                    const int orow = tid >> 2;              // 0..63
                    const int oc = (tid & 3) << 5;          // 0,32,64,96 ushorts
                    const int grow = row0 + (half << 6) + orow;
                    if (grow < M) {
                        const uint4* sp = (const uint4*)(scratch + orow * 136 + oc);
                        uint4* dp = (uint4*)(Z + (size_t)grow * N + col0 + oc);
#pragma unroll
                        for (int q = 0; q < 4; ++q) dp[q] = sp[q];
                    }
                    asm volatile("s_waitcnt lgkmcnt(0)" ::: "memory");  // reads done
                    __builtin_amdgcn_s_barrier();
                }
            } else {
#pragma unroll
                for (int n = 0; n < 4; ++n) {
                    const int col = col0 + (wc << 6) + (n << 4) + lr;
                    const float bv = bias[col];
#pragma unroll
                    for (int m = 0; m < 4; ++m) {
                        const int rw = row0 + (wr << 6) + (m << 4) + rgrp;
#pragma unroll
                        for (int j = 0; j < 4; ++j) {
                            const int row = rw + j;
                            if (row < M) C[(size_t)row * N + col] = acc[m][n][j] + bv;
                        }
                    }
                }
            }
#pragma unroll
            for (int m = 0; m < 4; ++m)
#pragma unroll
                for (int n = 0; n < 4; ++n) acc[m][n] = (floatx4){0.f, 0.f, 0.f, 0.f};
        }

        if (s + 2 < S) stage(s + 2);     // into buffer (s&1) — epilogue scratch freed
    }
}

// ------- pool: sorted-batch segment mean over bf16 h -> bf16 [g][HDIM] -------
__global__ void pool_kernel(const unsigned short* __restrict__ h,
                            const int* __restrict__ batch,
                            unsigned short* __restrict__ gz) {
    __shared__ int sse[2];
    const int g = blockIdx.x;
    if (threadIdx.x < 2) {
        const int target = g + threadIdx.x;
        int lo = 0, hi = N_NODES;
        while (lo < hi) {
            const int mid = (lo + hi) >> 1;
            if (batch[mid] < target) lo = mid + 1; else hi = mid;
        }
        sse[threadIdx.x] = lo;
    }
    __syncthreads();
    const int s = sse[0], e = sse[1];
    const int j = threadIdx.x;
    float acc = 0.f;
    for (int n = s; n < e; ++n) acc += bf2f(h[(size_t)n * HDIM + j]);
    const float v = acc * ((e > s) ? 1.f / (float)(e - s) : 1.f);
    gz[(size_t)g * HDIM + j] = f2bf(v);
}

extern "C" void kernel_launch(void* const* d_in, const int* in_sizes, int n_in,
                              void* d_out, int out_size, void* d_ws, size_t ws_size,
                              hipStream_t stream) {
    const float* x      = (const float*)d_in[0];
    const int*   eidx   = (const int*)d_in[1];
    const int*   batch  = (const int*)d_in[2];
    const float* W_atom = (const float*)d_in[3];
    const float* b_atom = (const float*)d_in[4];
    const float* W1     = (const float*)d_in[5];
    const float* b1     = (const float*)d_in[6];
    const float* W2     = (const float*)d_in[7];
    const float* b2     = (const float*)d_in[8];
    const float* Wf1    = (const float*)d_in[9];
    const float* bf1    = (const float*)d_in[10];
    const float* Wf2    = (const float*)d_in[11];
    const float* bf2    = (const float*)d_in[12];
    float* out = (float*)d_out;

    const int* src = eidx;
    const int* dst = eidx + N_EDGES;

    const size_t NH = (size_t)N_NODES * HDIM;           // 25.6M elems
    const int WSZ = HDIM * 2 * HDIM;                    // 131072 elems per layer weight

    // ---- workspace layout ----
    char* base = (char*)d_ws;
    size_t off = 0;
    unsigned short* h = (unsigned short*)(base + off);      off += NH * 2;  // bf16 [N][256]
    unsigned short* zin = (unsigned short*)(base + off);    off += NH * 2;  // bf16 [N][256]
    unsigned short* xb = (unsigned short*)(base + off);     off += (size_t)N_NODES * 64 * 2;
    int* deg     = (int*)(base + off);            off += (size_t)N_NODES * 4;
    int* row_ptr = (int*)(base + off);            off += (size_t)(N_NODES + 1) * 4;
    int* cursor  = (int*)(base + off);            off += (size_t)N_NODES * 4;
    int* eids    = (int*)(base + off);            off += (size_t)N_EDGES * 4;
    int* blk     = (int*)(base + off);            off += 512 * 4;
    off = (off + 255) & ~(size_t)255;
    unsigned short* t1 = (unsigned short*)(base + off); off += (size_t)NLAYERS * WSZ * 2;
    unsigned short* t2 = (unsigned short*)(base + off); off += (size_t)NLAYERS * WSZ * 2;
    unsigned short* tf1 = (unsigned short*)(base + off); off += (size_t)HDIM * HDIM * 2;
    unsigned short* tf2 = (unsigned short*)(base + off); off += (size_t)HDIM * EDIM * 2;
    unsigned short* tat = (unsigned short*)(base + off); off += (size_t)HDIM * 64 * 2;
    off = (off + 255) & ~(size_t)255;

    const size_t avail = (ws_size > off) ? ws_size - off : 0;
    long chunk = (long)(avail / ((size_t)EDIM * 2));       // z2 row = 512 bf16 = 1 KB
    if (chunk >= N_NODES) chunk = N_NODES;                 // single chunk (z2 102MB)
    else chunk &= ~127L;
    if (chunk < 128) chunk = 128;
    unsigned short* z2 = (unsigned short*)(base + off);    // [chunk][512] bf16

    // head buffers overlap the (dead-after-layers) zin region
    const size_t GH = (size_t)N_GRAPHS * HDIM;
    unsigned short* hg  = zin;            // [4000][256] bf16
    unsigned short* hg1 = zin + GH;       // [4000][256] bf16

    const int nb = (N_NODES + 255) / 256;
    const int NBLK_MAX = 512;                              // 2 blocks/CU x 256 CU

    auto launch_cfg = [&](int M, int N, int& nblk, int& tpb) {
        const int ntile = ((M + 127) / 128) * (N / 128);
        nblk = (ntile < NBLK_MAX) ? ntile : NBLK_MAX;
        tpb = (ntile + nblk - 1) / nblk;
    };

    // 1. x -> bf16 padded [N][64]; weights -> transposed bf16 (one dispatch each)
    xprep_kernel<<<1024, 256, 0, stream>>>(x, xb);
    wprep_all<<<1024, 256, 0, stream>>>(W1, W2, Wf1, Wf2, W_atom, t1, t2, tf1, tf2, tat);

    // 2. CSR build (+ deterministic segment sort)
    zero_kernel<<<128, 256, 0, stream>>>((float*)deg, N_NODES / 4);
    hist_kernel<<<(N_EDGES + 255) / 256, 256, 0, stream>>>(dst, deg);
    scan1_kernel<<<nb, 256, 0, stream>>>(deg, row_ptr, blk);
    scan2_kernel<<<1, 64, 0, stream>>>(blk, nb);
    scan3_kernel<<<nb, 256, 0, stream>>>(row_ptr, blk);
    cursor_kernel<<<nb, 256, 0, stream>>>(row_ptr, cursor);
    fill_kernel<<<(N_EDGES + 255) / 256, 256, 0, stream>>>(src, dst, cursor, eids);
    sort_kernel<<<nb, 256, 0, stream>>>(row_ptr, eids);   // deterministic gather order

    // 3. atom MLP as persistent GEMM: h = relu(xb @ W_atom + b_atom)  (NT=1 -> KK=64)
    {
        int nblk, tpb; launch_cfg(N_NODES, HDIM, nblk, tpb);
        gemm_mt<2, 1><<<nblk, 256, 0, stream>>>(
            xb, tat, b_atom, nullptr, h, N_NODES, HDIM, tpb);
    }

    // 4. GIN layers (unfused pair, both persistent multi-tile)
    for (int l = 0; l < NLAYERS; ++l) {
        gather_kernel<<<N_NODES / 4, 256, 0, stream>>>(h, row_ptr, eids, zin);
        for (long r0 = 0; r0 < N_NODES; r0 += chunk) {
            const int mc = (int)((N_NODES - r0 < chunk) ? (N_NODES - r0) : chunk);
            int nblk, tpb;
            // z2 = relu(zin @ W1[l] + b1[l])  [mc, 512], zin rows 256 -> NT=4 (KK=256)
            launch_cfg(mc, 2 * HDIM, nblk, tpb);
            gemm_mt<2, 4><<<nblk, 256, 0, stream>>>(
                zin + (size_t)r0 * HDIM, t1 + (size_t)l * WSZ,
                b1 + (size_t)l * 2 * HDIM, nullptr, z2, mc, 2 * HDIM, tpb);
            // h = relu(z2 @ W2[l] + b2[l])    [mc, 256], z2 rows 512 -> NT=8 (KK=512)
            launch_cfg(mc, HDIM, nblk, tpb);
            gemm_mt<2, 8><<<nblk, 256, 0, stream>>>(
                z2, t2 + (size_t)l * WSZ,
                b2 + (size_t)l * HDIM, nullptr, h + (size_t)r0 * HDIM, mc, HDIM, tpb);
        }
    }

    // 5. pool (bf16 in/out)
    pool_kernel<<<N_GRAPHS, HDIM, 0, stream>>>(h, batch, hg);

    // 6. head (hg/hg1 rows 256 -> NT=4 (KK=256))
    {
        int nblk, tpb; launch_cfg(N_GRAPHS, HDIM, nblk, tpb);
        gemm_mt<2, 4><<<nblk, 256, 0, stream>>>(
            hg, tf1, bf1, nullptr, hg1, N_GRAPHS, HDIM, tpb);
        launch_cfg(N_GRAPHS, EDIM, nblk, tpb);
        gemm_mt<0, 4><<<nblk, 256, 0, stream>>>(
            hg1, tf2, bf2, out, nullptr, N_GRAPHS, EDIM, tpb);
    }
}